// Round 1
// baseline (154.281 us; speedup 1.0000x reference)
//
#include <hip/hip_runtime.h>
#include <hip/hip_bf16.h>

#define B_ 2
#define S_ 2048
#define H_ 16
#define D_ 128
#define HD_ (H_ * D_)
#define KVB 64
#define NTILE (S_ / KVB)
#define BQ 128

typedef short bf16x8 __attribute__((ext_vector_type(8)));
typedef float f32x16 __attribute__((ext_vector_type(16)));

union BF8u { unsigned u[4]; bf16x8 v; };
union F4u { float4 v; float a[4]; };

__device__ __forceinline__ unsigned f2bfu(float x) {
    union { float f; unsigned u; } a; a.f = x;
    return (a.u + 0x7FFFu + ((a.u >> 16) & 1u)) >> 16;
}
__device__ __forceinline__ unsigned pk2(float lo, float hi) {
    return f2bfu(lo) | (f2bfu(hi) << 16);
}

__global__ __launch_bounds__(256, 2)
void attn_fwd_kernel(const float* __restrict__ qg,
                     const float* __restrict__ kg,
                     const float* __restrict__ vg,
                     float* __restrict__ outg,
                     float* __restrict__ lseg)
{
    __shared__ unsigned short Kb[2][KVB * D_];   // [kv][d] bf16, swizzled
    __shared__ unsigned short Vb[2][D_ * KVB];   // [d][kv] bf16 (V^T), swizzled

    const int tid = threadIdx.x;
    const int lane = tid & 63;
    const int wv = tid >> 6;
    const int rl = lane & 31;
    const int h2 = lane >> 5;

    // XCD-aware swizzle (512 = 8*64, bijective)
    const int bid = blockIdx.x;
    const int L = (bid & 7) * 64 + (bid >> 3);
    const int bh = L >> 4;
    const int qt = L & 15;
    const int b = bh >> 4, h = bh & 15;
    const int q0 = qt * BQ;

    const size_t base = (size_t)b * S_ * HD_ + (size_t)h * D_;

    // ---- Q fragments (B-operand layout: q=lane&31, d = 16*kt + 8*h2 + e), scaled by 1/sqrt(D)*log2(e)
    const float qscale = 0.08838834764831845f * 1.4426950408889634f;
    bf16x8 qf[8];
    {
        const float* qp = qg + base + (size_t)(q0 + wv * 32 + rl) * HD_;
        #pragma unroll
        for (int kt = 0; kt < 8; ++kt) {
            int d0 = kt * 16 + h2 * 8;
            float4 x = *(const float4*)(qp + d0);
            float4 y = *(const float4*)(qp + d0 + 4);
            BF8u t;
            t.u[0] = pk2(x.x * qscale, x.y * qscale);
            t.u[1] = pk2(x.z * qscale, x.w * qscale);
            t.u[2] = pk2(y.x * qscale, y.y * qscale);
            t.u[3] = pk2(y.z * qscale, y.w * qscale);
            qf[kt] = t.v;
        }
    }

    // staging thread maps
    const int krow = tid >> 2;          // 0..63 kv row
    const int kc0 = (tid & 3) * 32;     // d base (32 floats per thread per row)
    const int vdb = tid & 31;           // d-block (4 d per block)
    const int vkb0 = tid >> 5;          // 0..7, kv-blocks vkb0 and vkb0+8

    float4 kl[8];
    F4u vl[2][4];

    auto stage_load = [&](int kv0) {
        const float* kp = kg + base + (size_t)(kv0 + krow) * HD_ + kc0;
        #pragma unroll
        for (int ii = 0; ii < 8; ++ii) kl[ii] = *(const float4*)(kp + 4 * ii);
        #pragma unroll
        for (int ii = 0; ii < 2; ++ii) {
            int kvb = vkb0 + 8 * ii;
            const float* vp = vg + base + (size_t)(kv0 + 4 * kvb) * HD_ + 4 * vdb;
            #pragma unroll
            for (int i = 0; i < 4; ++i) vl[ii][i].v = *(const float4*)(vp + (size_t)i * HD_);
        }
    };

    auto stage_write = [&](int bufi) {
        char* kb = (char*)&Kb[bufi][0];
        #pragma unroll
        for (int ii = 0; ii < 8; ++ii) {
            int d0 = kc0 + 4 * ii;
            uint2 w;
            w.x = pk2(kl[ii].x, kl[ii].y);
            w.y = pk2(kl[ii].z, kl[ii].w);
            *(uint2*)(kb + ((krow * 256 + d0 * 2) ^ ((krow & 7) << 4))) = w;
        }
        char* vb = (char*)&Vb[bufi][0];
        #pragma unroll
        for (int ii = 0; ii < 2; ++ii) {
            int kvb = vkb0 + 8 * ii;
            #pragma unroll
            for (int j = 0; j < 4; ++j) {
                int d = 4 * vdb + j;
                uint2 w;
                w.x = pk2(vl[ii][0].a[j], vl[ii][1].a[j]);
                w.y = pk2(vl[ii][2].a[j], vl[ii][3].a[j]);
                *(uint2*)(vb + ((d * 128 + 8 * kvb) ^ ((d & 7) << 4))) = w;
            }
        }
    };

    f32x16 o0 = (f32x16)0.0f, o1 = (f32x16)0.0f, o2 = (f32x16)0.0f, o3 = (f32x16)0.0f;
    float m = -__builtin_inff(), lsum = 0.0f;

    stage_load(0);
    stage_write(0);
    __syncthreads();

    const int cswz = (rl & 7) << 4;

    for (int t = 0; t < NTILE; ++t) {
        const int cur = t & 1;
        const char* kb = (const char*)&Kb[cur][0];
        const char* vb = (const char*)&Vb[cur][0];

        // ---- QK^T (swapped): S^T[kv][q] = K · Q^T ; A = K tile rows, B = Q frags
        f32x16 s0 = (f32x16)0.0f, s1 = (f32x16)0.0f;
        #pragma unroll
        for (int kt = 0; kt < 8; ++kt) {
            int cb = kt * 32 + h2 * 16;   // byte col = (16*kt + 8*h2)*2
            bf16x8 a0 = *(const bf16x8*)(kb + ((rl * 256 + cb) ^ cswz));
            bf16x8 a1 = *(const bf16x8*)(kb + (((rl + 32) * 256 + cb) ^ cswz));
            s0 = __builtin_amdgcn_mfma_f32_32x32x16_bf16(a0, qf[kt], s0, 0, 0, 0);
            s1 = __builtin_amdgcn_mfma_f32_32x32x16_bf16(a1, qf[kt], s1, 0, 0, 0);
        }

        // ---- online softmax, log2 domain; lane's q-row = lane&31
        float pmax = s0[0];
        #pragma unroll
        for (int r = 1; r < 16; ++r) pmax = fmaxf(pmax, s0[r]);
        #pragma unroll
        for (int r = 0; r < 16; ++r) pmax = fmaxf(pmax, s1[r]);
        pmax = fmaxf(pmax, __shfl_xor(pmax, 32));

        if (__any(pmax > m + 8.0f)) {       // defer-max (T13)
            float mn = fmaxf(m, pmax);
            float al = __builtin_amdgcn_exp2f(m - mn);
            m = mn;
            lsum *= al;
            #pragma unroll
            for (int r = 0; r < 16; ++r) {
                float ar = __shfl(al, (r & 3) + 8 * (r >> 2) + 4 * h2);
                o0[r] *= ar; o1[r] *= ar; o2[r] *= ar; o3[r] *= ar;
            }
        }

        float ps = 0.0f;
        #pragma unroll
        for (int r = 0; r < 16; ++r) { float e = __builtin_amdgcn_exp2f(s0[r] - m); s0[r] = e; ps += e; }
        #pragma unroll
        for (int r = 0; r < 16; ++r) { float e = __builtin_amdgcn_exp2f(s1[r] - m); s1[r] = e; ps += e; }
        lsum += ps;

        // ---- pack P (C-layout, kv = 32*t2 + 8*u + 4*h2 + j) into PV A-fragments
        // pa[ks]: q = lane&31, kv = 16*ks + 8*h2 + e (e ascending)
        unsigned c0w[2][4], c1w[2][4];
        #pragma unroll
        for (int u = 0; u < 4; ++u) {
            c0w[0][u] = pk2(s0[4 * u], s0[4 * u + 1]);
            c1w[0][u] = pk2(s0[4 * u + 2], s0[4 * u + 3]);
            c0w[1][u] = pk2(s1[4 * u], s1[4 * u + 1]);
            c1w[1][u] = pk2(s1[4 * u + 2], s1[4 * u + 3]);
        }
        bf16x8 pa[4];
        #pragma unroll
        for (int ks = 0; ks < 4; ++ks) {
            const int t2 = ks >> 1, ue = (ks & 1) * 2, uo = ue + 1;
            unsigned pe0 = (unsigned)__shfl_xor((int)c0w[t2][ue], 32);
            unsigned pe1 = (unsigned)__shfl_xor((int)c1w[t2][ue], 32);
            unsigned po0 = (unsigned)__shfl_xor((int)c0w[t2][uo], 32);
            unsigned po1 = (unsigned)__shfl_xor((int)c1w[t2][uo], 32);
            BF8u pt;
            pt.u[0] = h2 ? po0 : c0w[t2][ue];
            pt.u[1] = h2 ? po1 : c1w[t2][ue];
            pt.u[2] = h2 ? c0w[t2][uo] : pe0;
            pt.u[3] = h2 ? c1w[t2][uo] : pe1;
            pa[ks] = pt.v;
        }

        // issue next tile's global loads so HBM latency hides under PV (T14-lite)
        if (t + 1 < NTILE) stage_load((t + 1) * KVB);

        // ---- PV: O[q][d] += P·V ; B-operand from V^T rows d = 32*mt + rl
        #pragma unroll
        for (int ks = 0; ks < 4; ++ks) {
            int cb = ks * 32 + h2 * 16;   // byte col = (16*ks + 8*h2)*2
            bf16x8 v0 = *(const bf16x8*)(vb + ((rl * 128 + cb) ^ cswz));
            bf16x8 v1 = *(const bf16x8*)(vb + (((rl + 32) * 128 + cb) ^ cswz));
            bf16x8 v2 = *(const bf16x8*)(vb + (((rl + 64) * 128 + cb) ^ cswz));
            bf16x8 v3 = *(const bf16x8*)(vb + (((rl + 96) * 128 + cb) ^ cswz));
            o0 = __builtin_amdgcn_mfma_f32_32x32x16_bf16(pa[ks], v0, o0, 0, 0, 0);
            o1 = __builtin_amdgcn_mfma_f32_32x32x16_bf16(pa[ks], v1, o1, 0, 0, 0);
            o2 = __builtin_amdgcn_mfma_f32_32x32x16_bf16(pa[ks], v2, o2, 0, 0, 0);
            o3 = __builtin_amdgcn_mfma_f32_32x32x16_bf16(pa[ks], v3, o3, 0, 0, 0);
        }

        if (t + 1 < NTILE) stage_write(cur ^ 1);
        __syncthreads();
    }

    // ---- epilogue: LSE + normalized O
    float lt = lsum + __shfl_xor(lsum, 32);
    float inv = 1.0f / lt;
    float lsev = (m + __builtin_amdgcn_logf(lt)) * 0.6931471805599453f;
    if (lane < 32) {
        lseg[(size_t)(b * H_ + h) * S_ + q0 + wv * 32 + rl] = lsev;
    }
    float ir[16];
    #pragma unroll
    for (int r = 0; r < 16; ++r) ir[r] = __shfl(inv, (r & 3) + 8 * (r >> 2) + 4 * h2);

    float* op = outg + base + (size_t)(q0 + wv * 32) * HD_ + rl;
    #pragma unroll
    for (int r = 0; r < 16; ++r) {
        int row = (r & 3) + 8 * (r >> 2) + 4 * h2;
        float* orow = op + (size_t)row * HD_;
        orow[0]  = o0[r] * ir[r];
        orow[32] = o1[r] * ir[r];
        orow[64] = o2[r] * ir[r];
        orow[96] = o3[r] * ir[r];
    }
}

extern "C" void kernel_launch(void* const* d_in, const int* in_sizes, int n_in,
                              void* d_out, int out_size, void* d_ws, size_t ws_size,
                              hipStream_t stream)
{
    const float* q = (const float*)d_in[0];
    const float* k = (const float*)d_in[1];
    const float* v = (const float*)d_in[2];
    float* out = (float*)d_out;
    float* lse = out + (size_t)B_ * S_ * H_ * D_;
    attn_fwd_kernel<<<dim3(B_ * H_ * (S_ / BQ)), dim3(256), 0, stream>>>(q, k, v, out, lse);
}

// Round 2
// 147.022 us; speedup vs baseline: 1.0494x; 1.0494x over previous
//
#include <hip/hip_runtime.h>
#include <hip/hip_bf16.h>

#define B_ 2
#define S_ 2048
#define H_ 16
#define D_ 128
#define HD_ (H_ * D_)
#define KVB 64
#define NTILE (S_ / KVB)
#define BQ 128

typedef short bf16x8 __attribute__((ext_vector_type(8)));
typedef float f32x16 __attribute__((ext_vector_type(16)));

union BF8u { unsigned u[4]; bf16x8 v; };
union F4u { float4 v; float x4[4]; };

__device__ __forceinline__ unsigned pk2(float lo, float hi) {
    __hip_bfloat162 h = __float22bfloat162_rn(make_float2(lo, hi));
    union { __hip_bfloat162 h; unsigned u; } c; c.h = h;
    return c.u;
}

__global__ __launch_bounds__(256, 2)
void attn_fwd_kernel(const float* __restrict__ qg,
                     const float* __restrict__ kg,
                     const float* __restrict__ vg,
                     float* __restrict__ outg,
                     float* __restrict__ lseg)
{
    __shared__ unsigned short Kb[2][KVB * D_];   // [kv][d] bf16, swizzled
    __shared__ unsigned short Vb[2][D_ * KVB];   // [d][kv] bf16 (V^T), swizzled

    const int tid = threadIdx.x;
    const int lane = tid & 63;
    const int wv = tid >> 6;
    const int rl = lane & 31;
    const int h2 = lane >> 5;

    // XCD-aware swizzle (512 = 8*64, bijective)
    const int bid = blockIdx.x;
    const int L = (bid & 7) * 64 + (bid >> 3);
    const int bh = L >> 4;
    const int qt = L & 15;
    const int b = bh >> 4, h = bh & 15;
    const int q0 = qt * BQ;

    const size_t base = (size_t)b * S_ * HD_ + (size_t)h * D_;

    // ---- staging thread maps (phase-conflict-free; see R1 post-mortem)
    // K: thread covers row krow, 8 chunks of 4 floats at col 4*(kc+4*ii)
    const int krow = tid >> 2;                    // 0..63
    const int kc = tid & 3;
    // V: 8kv x 4d microtile at (8*va, 4*vbc)
    const int va = (tid & 3) | ((tid >> 7) << 2); // 0..7 kv-slot
    const int vbc = (tid >> 2) & 31;              // 0..31 d-block

    float4 kl[8];
    F4u vl[8];

    auto stage_load = [&](int kv0) {
        const float* kp = kg + base + (size_t)(kv0 + krow) * HD_ + 4 * kc;
        #pragma unroll
        for (int ii = 0; ii < 8; ++ii) kl[ii] = *(const float4*)(kp + 16 * ii);
        const float* vp = vg + base + (size_t)(kv0 + 8 * va) * HD_ + 4 * vbc;
        #pragma unroll
        for (int i = 0; i < 8; ++i) vl[i].v = *(const float4*)(vp + (size_t)i * HD_);
    };

    auto stage_write = [&](int bufi) {
        char* kb = (char*)&Kb[bufi][0];
        const int kswz = (krow & 7) << 4;
        #pragma unroll
        for (int ii = 0; ii < 8; ++ii) {
            int dby = 8 * (kc + 4 * ii);          // byte col in row
            uint2 w;
            w.x = pk2(kl[ii].x, kl[ii].y);
            w.y = pk2(kl[ii].z, kl[ii].w);
            *(uint2*)(kb + ((krow * 256 + dby) ^ kswz)) = w;
        }
        char* vbuf = (char*)&Vb[bufi][0];
        #pragma unroll
        for (int j = 0; j < 4; ++j) {
            int d = 4 * vbc + j;
            uint4 w;
            w.x = pk2(vl[0].x4[j], vl[1].x4[j]);
            w.y = pk2(vl[2].x4[j], vl[3].x4[j]);
            w.z = pk2(vl[4].x4[j], vl[5].x4[j]);
            w.w = pk2(vl[6].x4[j], vl[7].x4[j]);
            *(uint4*)(vbuf + ((d * 128 + 16 * va) ^ ((d & 7) << 4))) = w;
        }
    };

    // ---- prologue: issue first tile loads, then Q fragments (overlaps latency)
    stage_load(0);

    // Q fragments (B-operand: q=lane&31, d = 16*kt + 8*h2 + e), scale*log2(e)
    const float qscale = 0.08838834764831845f * 1.4426950408889634f;
    bf16x8 qf[8];
    {
        const float* qp = qg + base + (size_t)(q0 + wv * 32 + rl) * HD_;
        #pragma unroll
        for (int kt = 0; kt < 8; ++kt) {
            int d0 = kt * 16 + h2 * 8;
            float4 x = *(const float4*)(qp + d0);
            float4 y = *(const float4*)(qp + d0 + 4);
            BF8u t;
            t.u[0] = pk2(x.x * qscale, x.y * qscale);
            t.u[1] = pk2(x.z * qscale, x.w * qscale);
            t.u[2] = pk2(y.x * qscale, y.y * qscale);
            t.u[3] = pk2(y.z * qscale, y.w * qscale);
            qf[kt] = t.v;
        }
    }

    stage_write(0);
    __syncthreads();

    f32x16 o0 = (f32x16)0.0f, o1 = (f32x16)0.0f, o2 = (f32x16)0.0f, o3 = (f32x16)0.0f;
    float m = -__builtin_inff(), lsum = 0.0f;

    const int cswz = (rl & 7) << 4;

    for (int t = 0; t < NTILE; ++t) {
        const int cur = t & 1;
        const char* kb = (const char*)&Kb[cur][0];
        const char* vb = (const char*)&Vb[cur][0];

        // issue next tile's global loads first: full-tile latency hiding
        if (t + 1 < NTILE) stage_load((t + 1) * KVB);

        // ---- QK^T (swapped): S^T[kv][q] = K · Q^T
        f32x16 s0 = (f32x16)0.0f, s1 = (f32x16)0.0f;
        __builtin_amdgcn_s_setprio(1);
        #pragma unroll
        for (int kt = 0; kt < 8; ++kt) {
            int cb = kt * 32 + h2 * 16;
            bf16x8 a0 = *(const bf16x8*)(kb + ((rl * 256 + cb) ^ cswz));
            bf16x8 a1 = *(const bf16x8*)(kb + (((rl + 32) * 256 + cb) ^ cswz));
            s0 = __builtin_amdgcn_mfma_f32_32x32x16_bf16(a0, qf[kt], s0, 0, 0, 0);
            s1 = __builtin_amdgcn_mfma_f32_32x32x16_bf16(a1, qf[kt], s1, 0, 0, 0);
        }
        __builtin_amdgcn_s_setprio(0);

        // ---- online softmax (log2 domain); lane's q-row = lane&31
        float r8[8];
        #pragma unroll
        for (int i = 0; i < 8; ++i)
            r8[i] = fmaxf(fmaxf(s0[i], s0[i + 8]), fmaxf(s1[i], s1[i + 8]));
        float r4a = fmaxf(r8[0], r8[4]), r4b = fmaxf(r8[1], r8[5]);
        float r4c = fmaxf(r8[2], r8[6]), r4d = fmaxf(r8[3], r8[7]);
        float pmax = fmaxf(fmaxf(r4a, r4b), fmaxf(r4c, r4d));
        pmax = fmaxf(pmax, __shfl_xor(pmax, 32));

        if (__any(pmax > m + 8.0f)) {       // defer-max (T13)
            float mn = fmaxf(m, pmax);
            float al = __builtin_amdgcn_exp2f(m - mn);
            m = mn;
            lsum *= al;
            #pragma unroll
            for (int r = 0; r < 16; ++r) {
                float ar = __shfl(al, (r & 3) + 8 * (r >> 2) + 4 * h2);
                o0[r] *= ar; o1[r] *= ar; o2[r] *= ar; o3[r] *= ar;
            }
        }

        float ps = 0.0f;
        #pragma unroll
        for (int r = 0; r < 16; ++r) { float e = __builtin_amdgcn_exp2f(s0[r] - m); s0[r] = e; ps += e; }
        #pragma unroll
        for (int r = 0; r < 16; ++r) { float e = __builtin_amdgcn_exp2f(s1[r] - m); s1[r] = e; ps += e; }
        lsum += ps;

        // ---- pack P into PV A-fragments: pa[ks]: q=lane&31, kv = 16*ks + 8*h2 + e
        unsigned c0w[2][4], c1w[2][4];
        #pragma unroll
        for (int u = 0; u < 4; ++u) {
            c0w[0][u] = pk2(s0[4 * u], s0[4 * u + 1]);
            c1w[0][u] = pk2(s0[4 * u + 2], s0[4 * u + 3]);
            c0w[1][u] = pk2(s1[4 * u], s1[4 * u + 1]);
            c1w[1][u] = pk2(s1[4 * u + 2], s1[4 * u + 3]);
        }
        bf16x8 pa[4];
        #pragma unroll
        for (int ks = 0; ks < 4; ++ks) {
            const int t2 = ks >> 1, ue = (ks & 1) * 2, uo = ue + 1;
            unsigned pe0 = (unsigned)__shfl_xor((int)c0w[t2][ue], 32);
            unsigned pe1 = (unsigned)__shfl_xor((int)c1w[t2][ue], 32);
            unsigned po0 = (unsigned)__shfl_xor((int)c0w[t2][uo], 32);
            unsigned po1 = (unsigned)__shfl_xor((int)c1w[t2][uo], 32);
            BF8u pt;
            pt.u[0] = h2 ? po0 : c0w[t2][ue];
            pt.u[1] = h2 ? po1 : c1w[t2][ue];
            pt.u[2] = h2 ? c0w[t2][uo] : pe0;
            pt.u[3] = h2 ? c1w[t2][uo] : pe1;
            pa[ks] = pt.v;
        }

        // ---- PV: O[q][d] += P·V from V^T rows d = 32*mt + rl
        __builtin_amdgcn_s_setprio(1);
        #pragma unroll
        for (int ks = 0; ks < 4; ++ks) {
            int cb = ks * 32 + h2 * 16;
            bf16x8 v0 = *(const bf16x8*)(vb + ((rl * 128 + cb) ^ cswz));
            bf16x8 v1 = *(const bf16x8*)(vb + (((rl + 32) * 128 + cb) ^ cswz));
            bf16x8 v2 = *(const bf16x8*)(vb + (((rl + 64) * 128 + cb) ^ cswz));
            bf16x8 v3 = *(const bf16x8*)(vb + (((rl + 96) * 128 + cb) ^ cswz));
            o0 = __builtin_amdgcn_mfma_f32_32x32x16_bf16(pa[ks], v0, o0, 0, 0, 0);
            o1 = __builtin_amdgcn_mfma_f32_32x32x16_bf16(pa[ks], v1, o1, 0, 0, 0);
            o2 = __builtin_amdgcn_mfma_f32_32x32x16_bf16(pa[ks], v2, o2, 0, 0, 0);
            o3 = __builtin_amdgcn_mfma_f32_32x32x16_bf16(pa[ks], v3, o3, 0, 0, 0);
        }
        __builtin_amdgcn_s_setprio(0);

        if (t + 1 < NTILE) stage_write(cur ^ 1);
        __syncthreads();
    }

    // ---- epilogue: LSE + normalized O
    float lt = lsum + __shfl_xor(lsum, 32);
    float inv = 1.0f / lt;
    float lsev = (m + __builtin_amdgcn_logf(lt)) * 0.6931471805599453f;
    if (lane < 32) {
        lseg[(size_t)(b * H_ + h) * S_ + q0 + wv * 32 + rl] = lsev;
    }
    float ir[16];
    #pragma unroll
    for (int r = 0; r < 16; ++r) ir[r] = __shfl(inv, (r & 3) + 8 * (r >> 2) + 4 * h2);

    float* op = outg + base + (size_t)(q0 + wv * 32) * HD_ + rl;
    #pragma unroll
    for (int r = 0; r < 16; ++r) {
        int row = (r & 3) + 8 * (r >> 2) + 4 * h2;
        float* orow = op + (size_t)row * HD_;
        orow[0]  = o0[r] * ir[r];
        orow[32] = o1[r] * ir[r];
        orow[64] = o2[r] * ir[r];
        orow[96] = o3[r] * ir[r];
    }
}

extern "C" void kernel_launch(void* const* d_in, const int* in_sizes, int n_in,
                              void* d_out, int out_size, void* d_ws, size_t ws_size,
                              hipStream_t stream)
{
    const float* q = (const float*)d_in[0];
    const float* k = (const float*)d_in[1];
    const float* v = (const float*)d_in[2];
    float* out = (float*)d_out;
    float* lse = out + (size_t)B_ * S_ * H_ * D_;
    attn_fwd_kernel<<<dim3(B_ * H_ * (S_ / BQ)), dim3(256), 0, stream>>>(q, k, v, out, lse);
}